// Round 15
// baseline (229.875 us; speedup 1.0000x reference)
//
#include <hip/hip_runtime.h>
#include <math.h>

#define H 256

typedef __attribute__((ext_vector_type(8))) short bf16x8;
typedef __attribute__((ext_vector_type(4))) float f32x4;
typedef __attribute__((ext_vector_type(4))) short short4v;

__device__ __forceinline__ short f2bf(float f) {
  union { float f; unsigned u; } x;
  x.f = f;
  unsigned r = x.u + 0x7fffu + ((x.u >> 16) & 1u);
  return (short)(r >> 16);
}
__device__ __forceinline__ float bf2f(short s) {
  union { float f; unsigned u; } x;
  x.u = ((unsigned)(unsigned short)s) << 16;
  return x.f;
}

// ---------------- gather + convert: d0bf[i] = bf16(x[map[i]]) ----------------
__global__ __launch_bounds__(256) void gather_cvt_kernel(const float4* __restrict__ x,
                                                         const int* __restrict__ map,
                                                         short4v* __restrict__ out, int n) {
  int total = n * (H / 4);
  for (int idx = blockIdx.x * blockDim.x + threadIdx.x; idx < total;
       idx += gridDim.x * blockDim.x) {
    int e = idx >> 6;
    int q = idx & 63;
    float4 v = x[(size_t)map[e] * 64 + q];
    short4v s;
    s[0] = f2bf(v.x); s[1] = f2bf(v.y); s[2] = f2bf(v.z); s[3] = f2bf(v.w);
    out[idx] = s;
  }
}

// ------- merged weights prep: combined Wc_z/Wc_s + bf16 W_p/W_pf + zeroing ----
__global__ __launch_bounds__(256) void wprep_kernel(
    const float* __restrict__ Wz, const float* __restrict__ Wzint,
    const float* __restrict__ Ws, const float* __restrict__ Wsint,
    const float* __restrict__ Wp, const float* __restrict__ Wpf,
    short* __restrict__ Wbf, int* __restrict__ zero_base) {
  int bid = blockIdx.x;
  int tid = threadIdx.x;
  if (bid < 2048) {
    const float* Wint = (bid < 1024) ? Wzint : Wsint;
    const float* W1 = (bid < 1024) ? Wz : Ws;
    short* out = Wbf + ((bid < 1024) ? 131072 : 393216);
    int b = bid & 1023;
    int k = b >> 8, o = b & 255;
    const float* A = Wint + (size_t)o * 256;
    const float* B = W1 + (size_t)k * 65536;
    float acc = 0.f;
#pragma unroll 8
    for (int j = 0; j < 256; ++j) acc = fmaf(A[j], B[(size_t)j * 256 + tid], acc);
    out[((size_t)k * 256 + o) * 256 + tid] = f2bf(acc);
  } else if (bid < 2176) {
    int i4 = (bid - 2048) * 256 + tid;
    int e = i4 * 4;
    const float* src = (e < 65536) ? Wp : Wpf;
    int off = (e < 65536) ? e : e - 65536;
    float4 v = *(const float4*)(src + off);
    short4v o;
    o[0] = f2bf(v.x); o[1] = f2bf(v.y); o[2] = f2bf(v.z); o[3] = f2bf(v.w);
    *(short4v*)(Wbf + e) = o;
  } else {
    if (tid < 192) zero_base[tid] = 0;  // 256B counts + 512B zrow
  }
}

// ------- one pre-pass: bucket + per-segment tm2 + listF for ALL 3 layers -----
__device__ __forceinline__ void bucket_body(const int* __restrict__ tmask, int base,
                                            int m, int g, int r,
                                            int* __restrict__ lists,
                                            int* __restrict__ counts,
                                            int* __restrict__ tm2,
                                            int* __restrict__ listF,
                                            int* __restrict__ cntF) {
  __shared__ int lc[4];
  __shared__ int lbase[4];
  int tid = threadIdx.x;
  if (tid < 4) lc[tid] = 0;
  __syncthreads();
  int i = base * 256 + tid;
  int t = 0, rank = 0;
  bool ok = i < m;
  if (ok) {
    t = tmask[i];
    rank = atomicAdd(&lc[t], 1);
  }
  __syncthreads();
  if (tid < 4) lbase[tid] = atomicAdd(&counts[tid], lc[tid]);
  __syncthreads();
  if (ok) lists[t * m + lbase[t] + rank] = i;

  int s = i;
  if (s < g) {
    int t2 = 0;
    for (int j = 0; j < r; ++j) {
      int tt = tmask[s * r + j];
      t2 = tt > t2 ? tt : t2;
    }
    tm2[s] = t2;
    unsigned long long mask = __ballot(t2 == 1);
    if (t2 == 1) {
      int lane = tid & 63;
      unsigned long long lt = (lane == 0) ? 0ull : (~0ull >> (64 - lane));
      int rnk = __popcll(mask & lt);
      int leader = __ffsll((long long)mask) - 1;
      int b = 0;
      if (lane == leader) b = atomicAdd(cntF, __popcll(mask));
      b = __shfl(b, leader);
      listF[b + rnk] = s;
    }
  }
}

__global__ __launch_bounds__(256) void bucket_all_kernel(
    const int* __restrict__ tm0, const int* __restrict__ tm1, const int* __restrict__ tm2in,
    int* __restrict__ lists0, int* __restrict__ lists1, int* __restrict__ lists2,
    int* __restrict__ counts,  // [3][8]
    int* __restrict__ seg0, int* __restrict__ seg1, int* __restrict__ seg2,
    int* __restrict__ listF0, int* __restrict__ listF1, int* __restrict__ listF2) {
  int bid = blockIdx.x;
  if (bid < 256)
    bucket_body(tm0, bid, 65536, 32768, 2, lists0, counts, seg0, listF0, counts + 4);
  else if (bid < 384)
    bucket_body(tm1, bid - 256, 32768, 8192, 4, lists1, counts + 8, seg1, listF1, counts + 12);
  else
    bucket_body(tm2in, bid - 384, 8192, 2048, 4, lists2, counts + 16, seg2, listF2, counts + 20);
}

// ---------------- GEMM tile: 128 rows x 64 cols, K = NCH*256 -----------------
// B panel (kc,cg) = 32KB in a DOUBLE-BUFFERED LDS (2x32KB): panel kc+1's loads
// issue BEFORE kc's MFMA phase (latency hides under 64 MFMAs), LDS write after,
// ONE barrier per kc. A per-lane direct from global (XCD-sibling L2 reuse).
template <int NCH>
__device__ __forceinline__ void gemm_tile(const short* __restrict__ Abf,
                                          const int* __restrict__ om, int m,
                                          const int* __restrict__ list, int n,
                                          int rowbase, int cg,
                                          const short* __restrict__ W1,
                                          const short* __restrict__ zrow,
                                          short* __restrict__ temp, char* lds) {
  const int tid = threadIdx.x;
  const int lane = tid & 63;
  const int wave = tid >> 6;
  const int lr = lane & 15;
  const int kg = lane >> 4;
  const int wrow = rowbase + wave * 32;

  int cidx[2][NCH];
#pragma unroll
  for (int rt = 0; rt < 2; ++rt) {
    int i = wrow + rt * 16 + lr;
    int rid = (i < n) ? list[i] : -1;
#pragma unroll
    for (int k = 0; k < NCH; ++k) cidx[rt][k] = (rid >= 0) ? om[k * m + rid] : -1;
  }

  f32x4 acc[2][4];
#pragma unroll
  for (int rt = 0; rt < 2; ++rt)
#pragma unroll
    for (int c = 0; c < 4; ++c) {
      f32x4 z = {0.f, 0.f, 0.f, 0.f};
      acc[rt][c] = z;
    }

  // prologue: stage panel kc=0 into buffer 0
  {
    const char* p0 = (const char*)W1 + ((size_t)cg * 64) * 512;
    bf16x8 breg[8];
#pragma unroll
    for (int it = 0; it < 8; ++it)
      breg[it] = *(const bf16x8*)(p0 + it * 4096 + tid * 16);
#pragma unroll
    for (int it = 0; it < 8; ++it) {
      int idx = it * 4096 + tid * 16;
      int col = idx >> 9;
      *(bf16x8*)(lds + (idx ^ ((col & 7) << 4))) = breg[it];
    }
  }
  __syncthreads();

  for (int kc = 0; kc < NCH; ++kc) {
    char* curbuf = lds + (kc & 1) * 32768;

    // issue-early: panel kc+1 global loads (consumed after the MFMA phase)
    bf16x8 breg[8];
    if (kc + 1 < NCH) {
      const char* pn = (const char*)W1 + ((size_t)(kc + 1) * 256 + cg * 64) * 512;
#pragma unroll
      for (int it = 0; it < 8; ++it)
        breg[it] = *(const bf16x8*)(pn + it * 4096 + tid * 16);
    }

    const short* ap[2];
#pragma unroll
    for (int rt = 0; rt < 2; ++rt) {
      int c = cidx[rt][kc];
      ap[rt] = (c >= 0) ? (Abf + (size_t)c * 256 + kg * 8) : (zrow + kg * 8);
    }

#pragma unroll
    for (int ko = 0; ko < 8; ++ko) {
      bf16x8 a[2], b[4];
#pragma unroll
      for (int c = 0; c < 4; ++c) {
        int col = c * 16 + lr;
        int off = (col * 512 + ko * 64 + kg * 16) ^ ((col & 7) << 4);
        b[c] = *(const bf16x8*)(curbuf + off);
      }
#pragma unroll
      for (int rt = 0; rt < 2; ++rt) a[rt] = *(const bf16x8*)(ap[rt] + ko * 32);
#pragma unroll
      for (int rt = 0; rt < 2; ++rt)
#pragma unroll
        for (int c = 0; c < 4; ++c)
          acc[rt][c] =
              __builtin_amdgcn_mfma_f32_16x16x32_bf16(a[rt], b[c], acc[rt][c], 0, 0, 0);
    }

    // write-late: store panel kc+1 into the other buffer, then one barrier
    if (kc + 1 < NCH) {
      char* nb = lds + ((kc + 1) & 1) * 32768;
#pragma unroll
      for (int it = 0; it < 8; ++it) {
        int idx = it * 4096 + tid * 16;
        int col = idx >> 9;
        *(bf16x8*)(nb + (idx ^ ((col & 7) << 4))) = breg[it];
      }
      __syncthreads();
    }
  }

  // epilogue: bf16 stores to temp[list[i]][cg*64 ...]
#pragma unroll
  for (int rt = 0; rt < 2; ++rt) {
#pragma unroll
    for (int q = 0; q < 4; ++q) {
      int i2 = wrow + rt * 16 + kg * 4 + q;
      if (i2 >= n) continue;
      int row = list[i2];
      short* dst = temp + (size_t)row * 256 + cg * 64 + lr;
#pragma unroll
      for (int c = 0; c < 4; ++c) dst[c * 16] = f2bf(acc[rt][c][q]);
    }
  }
}

// ---------------- fused per-layer GEMM: capacity regions [t2][t3][t1][t0] ----
// t1/t2/t3: capacity c14 = (m/128)*4 items. XCD-aware decode: the 4 colgroup
// siblings of one rowtile sit at bids {b, b+8, b+16, b+24} (same bid%8 -> same
// XCD under round-robin dispatch) so gathered A rows L2-hit.
// t0: capacity m/64 copy items of 64 rows.
__global__ __launch_bounds__(256) void fused_gemm(
    const short* __restrict__ Abf, const int* __restrict__ om, int m,
    const int* __restrict__ lists, const int* __restrict__ counts,
    const short* __restrict__ Wp,
    const short* __restrict__ Wcz, const short* __restrict__ Wcs,
    const short* __restrict__ zrow,
    short* __restrict__ temp) {
  const int c14 = (m >> 7) << 2;  // (m/128)*4, multiple of 32 for all layers
  int bid = (int)blockIdx.x;
  __shared__ __align__(16) char lds[2 * 32768];  // 64 KB double-buffered B panel

  int type, item;
  if (bid < c14)            { type = 2; item = bid; }
  else if (bid < 2 * c14)   { type = 3; item = bid - c14; }
  else if (bid < 3 * c14)   { type = 1; item = bid - 2 * c14; }
  else                      { type = 0; item = bid - 3 * c14; }

  int n = counts[type];
  const int* list = lists + type * m;

  if (type == 0) {
    int rowbase = item * 64;
    if (rowbase >= n) return;
    int lim = n - rowbase;
    if (lim > 64) lim = 64;
    for (int idx = threadIdx.x; idx < lim * 32; idx += 256) {
      int e = rowbase + (idx >> 5);
      int q = idx & 31;
      int row = list[e];
      int c = om[row];
      bf16x8 v = {0, 0, 0, 0, 0, 0, 0, 0};
      if (c >= 0) v = *(const bf16x8*)(Abf + (size_t)c * 256 + q * 8);
      *(bf16x8*)(temp + (size_t)row * 256 + q * 8) = v;
    }
    return;
  }

  // XCD-aware decode: group of 32 items = 8 rowtiles x 4 colgroups.
  int rowtile = ((item >> 5) << 3) | (item & 7);
  int cg = (item >> 3) & 3;
  int rowbase = rowtile * 128;
  if (rowbase >= n) return;

  if (type == 1)
    gemm_tile<1>(Abf, om, m, list, n, rowbase, cg, Wp, zrow, temp, lds);
  else if (type == 2)
    gemm_tile<4>(Abf, om, m, list, n, rowbase, cg, Wcz, zrow, temp, lds);
  else
    gemm_tile<4>(Abf, om, m, list, n, rowbase, cg, Wcs, zrow, temp, lds);
}

// ------- segment reduce (contiguous r rows) + ELU + write next/out ----------
__global__ __launch_bounds__(256) void reduce_kernel(const short* __restrict__ temp,
                                                     int r, int g,
                                                     const int* __restrict__ tm2,
                                                     float* __restrict__ outf,
                                                     short* __restrict__ outbf) {
  int idx = blockIdx.x * 256 + threadIdx.x;
  if (idx >= g * 32) return;
  int s = idx >> 5;
  int q = idx & 31;
  float acc[8];
#pragma unroll
  for (int k = 0; k < 8; ++k) acc[k] = 0.f;
  for (int j = 0; j < r; ++j) {
    bf16x8 v = *(const bf16x8*)(temp + (size_t)(s * r + j) * 256 + q * 8);
#pragma unroll
    for (int k = 0; k < 8; ++k) acc[k] += bf2f(v[k]);
  }
  if (tm2[s] != 0) {
#pragma unroll
    for (int k = 0; k < 8; ++k) acc[k] = acc[k] > 0.f ? acc[k] : (expf(acc[k]) - 1.f);
  }
  if (outf) {
    float4 f0 = {acc[0], acc[1], acc[2], acc[3]};
    float4 f1 = {acc[4], acc[5], acc[6], acc[7]};
    *(float4*)(outf + (size_t)s * 256 + q * 8) = f0;
    *(float4*)(outf + (size_t)s * 256 + q * 8 + 4) = f1;
  }
  if (outbf) {
    bf16x8 o;
#pragma unroll
    for (int k = 0; k < 8; ++k) o[k] = f2bf(acc[k]);
    *(bf16x8*)(outbf + (size_t)s * 256 + q * 8) = o;
  }
}

// -------- tm2==1 segments: rows = rows @ W_pf^T in place ----------
template <int SRC>
__global__ __launch_bounds__(256) void pf_gemm(short* __restrict__ buf,
                                               float* __restrict__ fbuf,
                                               const int* __restrict__ listF,
                                               const int* __restrict__ cnt,
                                               const short* __restrict__ Wpf) {
  int n = *cnt;
  int rowbase = blockIdx.x * 32;
  if (rowbase >= n) return;
  const int lane = threadIdx.x & 63;
  const int wave = threadIdx.x >> 6;
  const int colbase = wave * 64;
  const int lr = lane & 15;
  const int kg = lane >> 4;

  int src[2];
#pragma unroll
  for (int rt = 0; rt < 2; ++rt) {
    int i = rowbase + rt * 16 + lr;
    src[rt] = (i < n) ? listF[i] : -1;
  }

  f32x4 acc[2][4];
#pragma unroll
  for (int rt = 0; rt < 2; ++rt)
#pragma unroll
    for (int c = 0; c < 4; ++c) {
      f32x4 z = {0.f, 0.f, 0.f, 0.f};
      acc[rt][c] = z;
    }

#pragma unroll 2
  for (int ko = 0; ko < 256; ko += 32) {
    bf16x8 b[4];
#pragma unroll
    for (int c = 0; c < 4; ++c)
      b[c] = *(const bf16x8*)(Wpf + (size_t)(colbase + c * 16 + lr) * 256 + ko + kg * 8);
#pragma unroll
    for (int rt = 0; rt < 2; ++rt) {
      bf16x8 a = {0, 0, 0, 0, 0, 0, 0, 0};
      if (src[rt] >= 0) {
        if (SRC == 0) {
          a = *(const bf16x8*)(buf + (size_t)src[rt] * 256 + ko + kg * 8);
        } else {
          const float* p = fbuf + (size_t)src[rt] * 256 + ko + kg * 8;
          float4 u0 = *(const float4*)p;
          float4 u1 = *(const float4*)(p + 4);
          a[0] = f2bf(u0.x); a[1] = f2bf(u0.y); a[2] = f2bf(u0.z); a[3] = f2bf(u0.w);
          a[4] = f2bf(u1.x); a[5] = f2bf(u1.y); a[6] = f2bf(u1.z); a[7] = f2bf(u1.w);
        }
      }
#pragma unroll
      for (int c = 0; c < 4; ++c)
        acc[rt][c] = __builtin_amdgcn_mfma_f32_16x16x32_bf16(a, b[c], acc[rt][c], 0, 0, 0);
    }
  }

  __syncthreads();  // all waves done READING these rows before any wave overwrites

#pragma unroll
  for (int rt = 0; rt < 2; ++rt) {
#pragma unroll
    for (int q = 0; q < 4; ++q) {
      int i2 = rowbase + rt * 16 + kg * 4 + q;
      if (i2 >= n) continue;
      int c2 = listF[i2];
      if (SRC == 0) {
        short* db = buf + (size_t)c2 * 256 + colbase + lr;
#pragma unroll
        for (int c = 0; c < 4; ++c) db[c * 16] = f2bf(acc[rt][c][q]);
      } else {
        float* df = fbuf + (size_t)c2 * 256 + colbase + lr;
#pragma unroll
        for (int c = 0; c < 4; ++c) df[c * 16] = acc[rt][c][q];
      }
    }
  }
}

// ---------------- host driver ----------------
extern "C" void kernel_launch(void* const* d_in, const int* in_sizes, int n_in,
                              void* d_out, int out_size, void* d_ws, size_t ws_size,
                              hipStream_t stream) {
  const float* x = (const float*)d_in[0];
  const int* initial_map = (const int*)d_in[1];
  const int* om[3] = {(const int*)d_in[2], (const int*)d_in[5], (const int*)d_in[8]};
  const int* tmask[3] = {(const int*)d_in[4], (const int*)d_in[7], (const int*)d_in[10]};
  const float* W_z = (const float*)d_in[11];
  const float* W_z_int = (const float*)d_in[12];
  const float* W_s = (const float*)d_in[13];
  const float* W_s_int = (const float*)d_in[14];
  const float* W_p = (const float*)d_in[15];
  const float* W_pf = (const float*)d_in[16];

  char* base = (char*)d_ws;
  // liveness-packed data buffers:
  short* d0bf  = (short*)(base);               // 32 MB: gather -> l0 fused
  short* temp0 = (short*)(base + 33554432);    // 32 MB: l0 fused -> l0 reduce
  short* d1bf  = (short*)(base);               // 16 MB: l0 reduce -> l1 fused
  short* temp1 = (short*)(base + 16777216);    // 16 MB: l1 fused -> l1 reduce
  short* d2bf  = (short*)(base + 33554432);    //  4 MB: l1 reduce -> l2 fused
  short* temp2 = (short*)(base + 37748736);    //  4 MB: l2 fused -> l2 reduce
  // persistent metadata region (from 64 MB up):
  size_t off = 67108864;
  short* Wbf = (short*)(base + off); off += 655360 * 2;       // 1.25 MB
  int* lists0 = (int*)(base + off); off += 4u * 65536 * 4;    // 1 MB
  int* lists1 = (int*)(base + off); off += 4u * 32768 * 4;    // 512 KB
  int* lists2 = (int*)(base + off); off += 4u * 8192 * 4;     // 128 KB
  int* listF0 = (int*)(base + off); off += 32768 * 4;
  int* listF1 = (int*)(base + off); off += 8192 * 4;
  int* listF2 = (int*)(base + off); off += 2048 * 4;
  int* seg0 = (int*)(base + off); off += 32768 * 4;
  int* seg1 = (int*)(base + off); off += 8192 * 4;
  int* seg2 = (int*)(base + off); off += 2048 * 4;
  int* counts = (int*)(base + off); off += 256;               // [3][8]
  short* zrow = (short*)(base + off); off += 512;             // 256 bf16 zeros

  short* Wp_bf  = Wbf + 0;
  short* Wpf_bf = Wbf + 65536;
  short* Wcz_bf = Wbf + 131072;   // [4][256][256] combined
  short* Wcs_bf = Wbf + 393216;   // [4][256][256] combined

  // wprep zeroes counts+zrow (contiguous) in its last block; runs before bucket_all.
  hipLaunchKernelGGL(wprep_kernel, dim3(2177), dim3(256), 0, stream, W_z, W_z_int,
                     W_s, W_s_int, W_p, W_pf, Wbf, counts);
  hipLaunchKernelGGL(bucket_all_kernel, dim3(416), dim3(256), 0, stream,
                     tmask[0], tmask[1], tmask[2], lists0, lists1, lists2, counts,
                     seg0, seg1, seg2, listF0, listF1, listF2);
  hipLaunchKernelGGL(gather_cvt_kernel, dim3(2048), dim3(256), 0, stream,
                     (const float4*)x, initial_map, (short4v*)d0bf, 65536);

  const int Ms[3] = {65536, 32768, 8192};
  const int Gs[3] = {32768, 8192, 2048};
  const short* dinbf[3] = {d0bf, d1bf, d2bf};
  short* tempL[3] = {temp0, temp1, temp2};
  short* nextbf[3] = {d1bf, d2bf, nullptr};
  int* listsL[3] = {lists0, lists1, lists2};
  int* listFL[3] = {listF0, listF1, listF2};
  int* segL[3] = {seg0, seg1, seg2};

  for (int l = 0; l < 3; ++l) {
    int m = Ms[l], g = Gs[l], r = m / g;
    int c14 = (m >> 7) << 2;
    int grid = 3 * c14 + m / 64;
    hipLaunchKernelGGL(fused_gemm, dim3(grid), dim3(256), 0, stream, dinbf[l], om[l],
                       m, listsL[l], counts + l * 8, Wp_bf, Wcz_bf, Wcs_bf, zrow,
                       tempL[l]);

    hipLaunchKernelGGL(reduce_kernel, dim3(g * 32 / 256), dim3(256), 0, stream,
                       tempL[l], r, g, segL[l], (l == 2) ? (float*)d_out : nullptr,
                       nextbf[l]);

    if (l < 2)
      hipLaunchKernelGGL((pf_gemm<0>), dim3(g / 32), dim3(256), 0, stream, nextbf[l],
                         (float*)nullptr, listFL[l], counts + l * 8 + 4, Wpf_bf);
    else
      hipLaunchKernelGGL((pf_gemm<1>), dim3(g / 32), dim3(256), 0, stream,
                         (short*)nullptr, (float*)d_out, listFL[l], counts + l * 8 + 4,
                         Wpf_bf);
  }
}

// Round 16
// 214.664 us; speedup vs baseline: 1.0709x; 1.0709x over previous
//
#include <hip/hip_runtime.h>
#include <math.h>

#define H 256

typedef __attribute__((ext_vector_type(8))) short bf16x8;
typedef __attribute__((ext_vector_type(4))) float f32x4;
typedef __attribute__((ext_vector_type(4))) short short4v;

__device__ __forceinline__ short f2bf(float f) {
  union { float f; unsigned u; } x;
  x.f = f;
  unsigned r = x.u + 0x7fffu + ((x.u >> 16) & 1u);
  return (short)(r >> 16);
}
__device__ __forceinline__ float bf2f(short s) {
  union { float f; unsigned u; } x;
  x.u = ((unsigned)(unsigned short)s) << 16;
  return x.f;
}

// ---------------- gather + convert: d0bf[i] = bf16(x[map[i]]) ----------------
__global__ __launch_bounds__(256) void gather_cvt_kernel(const float4* __restrict__ x,
                                                         const int* __restrict__ map,
                                                         short4v* __restrict__ out, int n) {
  int total = n * (H / 4);
  for (int idx = blockIdx.x * blockDim.x + threadIdx.x; idx < total;
       idx += gridDim.x * blockDim.x) {
    int e = idx >> 6;
    int q = idx & 63;
    float4 v = x[(size_t)map[e] * 64 + q];
    short4v s;
    s[0] = f2bf(v.x); s[1] = f2bf(v.y); s[2] = f2bf(v.z); s[3] = f2bf(v.w);
    out[idx] = s;
  }
}

// ------- merged weights prep: combined Wc_z/Wc_s + bf16 W_p/W_pf + zeroing ----
__global__ __launch_bounds__(256) void wprep_kernel(
    const float* __restrict__ Wz, const float* __restrict__ Wzint,
    const float* __restrict__ Ws, const float* __restrict__ Wsint,
    const float* __restrict__ Wp, const float* __restrict__ Wpf,
    short* __restrict__ Wbf, int* __restrict__ zero_base) {
  int bid = blockIdx.x;
  int tid = threadIdx.x;
  if (bid < 2048) {
    const float* Wint = (bid < 1024) ? Wzint : Wsint;
    const float* W1 = (bid < 1024) ? Wz : Ws;
    short* out = Wbf + ((bid < 1024) ? 131072 : 393216);
    int b = bid & 1023;
    int k = b >> 8, o = b & 255;
    const float* A = Wint + (size_t)o * 256;
    const float* B = W1 + (size_t)k * 65536;
    float acc = 0.f;
#pragma unroll 8
    for (int j = 0; j < 256; ++j) acc = fmaf(A[j], B[(size_t)j * 256 + tid], acc);
    out[((size_t)k * 256 + o) * 256 + tid] = f2bf(acc);
  } else if (bid < 2176) {
    int i4 = (bid - 2048) * 256 + tid;
    int e = i4 * 4;
    const float* src = (e < 65536) ? Wp : Wpf;
    int off = (e < 65536) ? e : e - 65536;
    float4 v = *(const float4*)(src + off);
    short4v o;
    o[0] = f2bf(v.x); o[1] = f2bf(v.y); o[2] = f2bf(v.z); o[3] = f2bf(v.w);
    *(short4v*)(Wbf + e) = o;
  } else {
    if (tid < 192) zero_base[tid] = 0;  // 256B counts + 512B zrow
  }
}

// ------- one pre-pass: bucket + per-segment tm2 + listF for ALL 3 layers -----
__device__ __forceinline__ void bucket_body(const int* __restrict__ tmask, int base,
                                            int m, int g, int r,
                                            int* __restrict__ lists,
                                            int* __restrict__ counts,
                                            int* __restrict__ tm2,
                                            int* __restrict__ listF,
                                            int* __restrict__ cntF) {
  __shared__ int lc[4];
  __shared__ int lbase[4];
  int tid = threadIdx.x;
  if (tid < 4) lc[tid] = 0;
  __syncthreads();
  int i = base * 256 + tid;
  int t = 0, rank = 0;
  bool ok = i < m;
  if (ok) {
    t = tmask[i];
    rank = atomicAdd(&lc[t], 1);
  }
  __syncthreads();
  if (tid < 4) lbase[tid] = atomicAdd(&counts[tid], lc[tid]);
  __syncthreads();
  if (ok) lists[t * m + lbase[t] + rank] = i;

  int s = i;
  if (s < g) {
    int t2 = 0;
    for (int j = 0; j < r; ++j) {
      int tt = tmask[s * r + j];
      t2 = tt > t2 ? tt : t2;
    }
    tm2[s] = t2;
    unsigned long long mask = __ballot(t2 == 1);
    if (t2 == 1) {
      int lane = tid & 63;
      unsigned long long lt = (lane == 0) ? 0ull : (~0ull >> (64 - lane));
      int rnk = __popcll(mask & lt);
      int leader = __ffsll((long long)mask) - 1;
      int b = 0;
      if (lane == leader) b = atomicAdd(cntF, __popcll(mask));
      b = __shfl(b, leader);
      listF[b + rnk] = s;
    }
  }
}

__global__ __launch_bounds__(256) void bucket_all_kernel(
    const int* __restrict__ tm0, const int* __restrict__ tm1, const int* __restrict__ tm2in,
    int* __restrict__ lists0, int* __restrict__ lists1, int* __restrict__ lists2,
    int* __restrict__ counts,  // [3][8]
    int* __restrict__ seg0, int* __restrict__ seg1, int* __restrict__ seg2,
    int* __restrict__ listF0, int* __restrict__ listF1, int* __restrict__ listF2) {
  int bid = blockIdx.x;
  if (bid < 256)
    bucket_body(tm0, bid, 65536, 32768, 2, lists0, counts, seg0, listF0, counts + 4);
  else if (bid < 384)
    bucket_body(tm1, bid - 256, 32768, 8192, 4, lists1, counts + 8, seg1, listF1, counts + 12);
  else
    bucket_body(tm2in, bid - 384, 8192, 2048, 4, lists2, counts + 16, seg2, listF2, counts + 20);
}

// ---------------- GEMM tile: 128 rows x 64 cols, K = NCH*256 -----------------
// (r14 body) B panel (kc, colgroup) = 32KB staged in LDS (XOR-swizzled).
// A fragments per-lane direct from global; colgroup-sibling blocks share an XCD
// so A rows are fetched from HBM once and re-served from that XCD's L2.
template <int NCH>
__device__ __forceinline__ void gemm_tile(const short* __restrict__ Abf,
                                          const int* __restrict__ om, int m,
                                          const int* __restrict__ list, int n,
                                          int rowbase, int cg,
                                          const short* __restrict__ W1,
                                          const short* __restrict__ zrow,
                                          short* __restrict__ temp, char* lds) {
  const int tid = threadIdx.x;
  const int lane = tid & 63;
  const int wave = tid >> 6;
  const int lr = lane & 15;
  const int kg = lane >> 4;
  const int wrow = rowbase + wave * 32;

  int cidx[2][NCH];
#pragma unroll
  for (int rt = 0; rt < 2; ++rt) {
    int i = wrow + rt * 16 + lr;
    int rid = (i < n) ? list[i] : -1;
#pragma unroll
    for (int k = 0; k < NCH; ++k) cidx[rt][k] = (rid >= 0) ? om[k * m + rid] : -1;
  }

  f32x4 acc[2][4];
#pragma unroll
  for (int rt = 0; rt < 2; ++rt)
#pragma unroll
    for (int c = 0; c < 4; ++c) {
      f32x4 z = {0.f, 0.f, 0.f, 0.f};
      acc[rt][c] = z;
    }

  for (int kc = 0; kc < NCH; ++kc) {
    const short* ap[2];
#pragma unroll
    for (int rt = 0; rt < 2; ++rt) {
      int c = cidx[rt][kc];
      ap[rt] = (c >= 0) ? (Abf + (size_t)c * 256 + kg * 8) : (zrow + kg * 8);
    }

    // stage B panel (kc, cg): contiguous 32KB -> LDS with XOR swizzle
    const char* psrc = (const char*)W1 + ((size_t)kc * 256 + cg * 64) * 512;
    __syncthreads();  // previous kc's LDS reads complete
#pragma unroll
    for (int it = 0; it < 8; ++it) {
      int idx = it * 4096 + tid * 16;
      bf16x8 v = *(const bf16x8*)(psrc + idx);
      int col = idx >> 9;
      *(bf16x8*)(lds + (idx ^ ((col & 7) << 4))) = v;
    }
    __syncthreads();  // panel ready

#pragma unroll
    for (int ko = 0; ko < 8; ++ko) {
      bf16x8 a[2], b[4];
#pragma unroll
      for (int c = 0; c < 4; ++c) {
        int col = c * 16 + lr;
        int off = (col * 512 + ko * 64 + kg * 16) ^ ((col & 7) << 4);
        b[c] = *(const bf16x8*)(lds + off);
      }
#pragma unroll
      for (int rt = 0; rt < 2; ++rt) a[rt] = *(const bf16x8*)(ap[rt] + ko * 32);
#pragma unroll
      for (int rt = 0; rt < 2; ++rt)
#pragma unroll
        for (int c = 0; c < 4; ++c)
          acc[rt][c] =
              __builtin_amdgcn_mfma_f32_16x16x32_bf16(a[rt], b[c], acc[rt][c], 0, 0, 0);
    }
  }

  // epilogue: bf16 stores to temp[list[i]][cg*64 ...]
#pragma unroll
  for (int rt = 0; rt < 2; ++rt) {
#pragma unroll
    for (int q = 0; q < 4; ++q) {
      int i2 = wrow + rt * 16 + kg * 4 + q;
      if (i2 >= n) continue;
      int row = list[i2];
      short* dst = temp + (size_t)row * 256 + cg * 64 + lr;
#pragma unroll
      for (int c = 0; c < 4; ++c) dst[c * 16] = f2bf(acc[rt][c][q]);
    }
  }
}

// ---------------- fused per-layer GEMM: DYNAMIC compact regions --------------
// Region capacities computed on-device from counts so active blocks form a
// contiguous bid prefix (dense co-residency). GEMM regions rounded to
// group-of-32 (8 rowtiles x 4 cg) preserving the XCD-sibling decode.
// Order: [t2][t3][t1][t0-copy]; tail bids exit immediately.
__global__ __launch_bounds__(256) void fused_gemm(
    const short* __restrict__ Abf, const int* __restrict__ om, int m,
    const int* __restrict__ lists, const int* __restrict__ counts,
    const short* __restrict__ Wp,
    const short* __restrict__ Wcz, const short* __restrict__ Wcs,
    const short* __restrict__ zrow,
    short* __restrict__ temp) {
  __shared__ __align__(16) char lds[64 * 512];  // exactly 32 KB

  int n0 = counts[0], n1 = counts[1], n2 = counts[2], n3 = counts[3];
  // items per GEMM region: ceil(rowtiles/8) groups of 32
  int c2 = ((((n2 + 127) >> 7) + 7) >> 3) << 5;
  int c3 = ((((n3 + 127) >> 7) + 7) >> 3) << 5;
  int c1 = ((((n1 + 127) >> 7) + 7) >> 3) << 5;
  int c0 = (n0 + 63) >> 6;
  int bid = (int)blockIdx.x;

  int type, item, n;
  if (bid < c2)                     { type = 2; item = bid;               n = n2; }
  else if (bid < c2 + c3)           { type = 3; item = bid - c2;          n = n3; }
  else if (bid < c2 + c3 + c1)      { type = 1; item = bid - c2 - c3;     n = n1; }
  else if (bid < c2 + c3 + c1 + c0) { type = 0; item = bid - c2 - c3 - c1; n = n0; }
  else return;

  const int* list = lists + type * m;

  if (type == 0) {
    int rowbase = item * 64;
    if (rowbase >= n) return;
    int lim = n - rowbase;
    if (lim > 64) lim = 64;
    for (int idx = threadIdx.x; idx < lim * 32; idx += 256) {
      int e = rowbase + (idx >> 5);
      int q = idx & 31;
      int row = list[e];
      int c = om[row];
      bf16x8 v = {0, 0, 0, 0, 0, 0, 0, 0};
      if (c >= 0) v = *(const bf16x8*)(Abf + (size_t)c * 256 + q * 8);
      *(bf16x8*)(temp + (size_t)row * 256 + q * 8) = v;
    }
    return;
  }

  // XCD-aware decode: group of 32 items = 8 rowtiles x 4 colgroups.
  int rowtile = ((item >> 5) << 3) | (item & 7);
  int cg = (item >> 3) & 3;
  int rowbase = rowtile * 128;
  if (rowbase >= n) return;

  if (type == 1)
    gemm_tile<1>(Abf, om, m, list, n, rowbase, cg, Wp, zrow, temp, lds);
  else if (type == 2)
    gemm_tile<4>(Abf, om, m, list, n, rowbase, cg, Wcz, zrow, temp, lds);
  else
    gemm_tile<4>(Abf, om, m, list, n, rowbase, cg, Wcs, zrow, temp, lds);
}

// ------- segment reduce (contiguous r rows) + ELU + write next/out ----------
__global__ __launch_bounds__(256) void reduce_kernel(const short* __restrict__ temp,
                                                     int r, int g,
                                                     const int* __restrict__ tm2,
                                                     float* __restrict__ outf,
                                                     short* __restrict__ outbf) {
  int idx = blockIdx.x * 256 + threadIdx.x;
  if (idx >= g * 32) return;
  int s = idx >> 5;
  int q = idx & 31;
  float acc[8];
#pragma unroll
  for (int k = 0; k < 8; ++k) acc[k] = 0.f;
  for (int j = 0; j < r; ++j) {
    bf16x8 v = *(const bf16x8*)(temp + (size_t)(s * r + j) * 256 + q * 8);
#pragma unroll
    for (int k = 0; k < 8; ++k) acc[k] += bf2f(v[k]);
  }
  if (tm2[s] != 0) {
#pragma unroll
    for (int k = 0; k < 8; ++k) acc[k] = acc[k] > 0.f ? acc[k] : (expf(acc[k]) - 1.f);
  }
  if (outf) {
    float4 f0 = {acc[0], acc[1], acc[2], acc[3]};
    float4 f1 = {acc[4], acc[5], acc[6], acc[7]};
    *(float4*)(outf + (size_t)s * 256 + q * 8) = f0;
    *(float4*)(outf + (size_t)s * 256 + q * 8 + 4) = f1;
  }
  if (outbf) {
    bf16x8 o;
#pragma unroll
    for (int k = 0; k < 8; ++k) o[k] = f2bf(acc[k]);
    *(bf16x8*)(outbf + (size_t)s * 256 + q * 8) = o;
  }
}

// -------- tm2==1 segments: rows = rows @ W_pf^T in place ----------
template <int SRC>
__global__ __launch_bounds__(256) void pf_gemm(short* __restrict__ buf,
                                               float* __restrict__ fbuf,
                                               const int* __restrict__ listF,
                                               const int* __restrict__ cnt,
                                               const short* __restrict__ Wpf) {
  int n = *cnt;
  int rowbase = blockIdx.x * 32;
  if (rowbase >= n) return;
  const int lane = threadIdx.x & 63;
  const int wave = threadIdx.x >> 6;
  const int colbase = wave * 64;
  const int lr = lane & 15;
  const int kg = lane >> 4;

  int src[2];
#pragma unroll
  for (int rt = 0; rt < 2; ++rt) {
    int i = rowbase + rt * 16 + lr;
    src[rt] = (i < n) ? listF[i] : -1;
  }

  f32x4 acc[2][4];
#pragma unroll
  for (int rt = 0; rt < 2; ++rt)
#pragma unroll
    for (int c = 0; c < 4; ++c) {
      f32x4 z = {0.f, 0.f, 0.f, 0.f};
      acc[rt][c] = z;
    }

#pragma unroll 2
  for (int ko = 0; ko < 256; ko += 32) {
    bf16x8 b[4];
#pragma unroll
    for (int c = 0; c < 4; ++c)
      b[c] = *(const bf16x8*)(Wpf + (size_t)(colbase + c * 16 + lr) * 256 + ko + kg * 8);
#pragma unroll
    for (int rt = 0; rt < 2; ++rt) {
      bf16x8 a = {0, 0, 0, 0, 0, 0, 0, 0};
      if (src[rt] >= 0) {
        if (SRC == 0) {
          a = *(const bf16x8*)(buf + (size_t)src[rt] * 256 + ko + kg * 8);
        } else {
          const float* p = fbuf + (size_t)src[rt] * 256 + ko + kg * 8;
          float4 u0 = *(const float4*)p;
          float4 u1 = *(const float4*)(p + 4);
          a[0] = f2bf(u0.x); a[1] = f2bf(u0.y); a[2] = f2bf(u0.z); a[3] = f2bf(u0.w);
          a[4] = f2bf(u1.x); a[5] = f2bf(u1.y); a[6] = f2bf(u1.z); a[7] = f2bf(u1.w);
        }
      }
#pragma unroll
      for (int c = 0; c < 4; ++c)
        acc[rt][c] = __builtin_amdgcn_mfma_f32_16x16x32_bf16(a, b[c], acc[rt][c], 0, 0, 0);
    }
  }

  __syncthreads();  // all waves done READING these rows before any wave overwrites

#pragma unroll
  for (int rt = 0; rt < 2; ++rt) {
#pragma unroll
    for (int q = 0; q < 4; ++q) {
      int i2 = rowbase + rt * 16 + kg * 4 + q;
      if (i2 >= n) continue;
      int c2 = listF[i2];
      if (SRC == 0) {
        short* db = buf + (size_t)c2 * 256 + colbase + lr;
#pragma unroll
        for (int c = 0; c < 4; ++c) db[c * 16] = f2bf(acc[rt][c][q]);
      } else {
        float* df = fbuf + (size_t)c2 * 256 + colbase + lr;
#pragma unroll
        for (int c = 0; c < 4; ++c) df[c * 16] = acc[rt][c][q];
      }
    }
  }
}

// ---------------- host driver ----------------
extern "C" void kernel_launch(void* const* d_in, const int* in_sizes, int n_in,
                              void* d_out, int out_size, void* d_ws, size_t ws_size,
                              hipStream_t stream) {
  const float* x = (const float*)d_in[0];
  const int* initial_map = (const int*)d_in[1];
  const int* om[3] = {(const int*)d_in[2], (const int*)d_in[5], (const int*)d_in[8]};
  const int* tmask[3] = {(const int*)d_in[4], (const int*)d_in[7], (const int*)d_in[10]};
  const float* W_z = (const float*)d_in[11];
  const float* W_z_int = (const float*)d_in[12];
  const float* W_s = (const float*)d_in[13];
  const float* W_s_int = (const float*)d_in[14];
  const float* W_p = (const float*)d_in[15];
  const float* W_pf = (const float*)d_in[16];

  char* base = (char*)d_ws;
  // liveness-packed data buffers:
  short* d0bf  = (short*)(base);               // 32 MB: gather -> l0 fused
  short* temp0 = (short*)(base + 33554432);    // 32 MB: l0 fused -> l0 reduce
  short* d1bf  = (short*)(base);               // 16 MB: l0 reduce -> l1 fused
  short* temp1 = (short*)(base + 16777216);    // 16 MB: l1 fused -> l1 reduce
  short* d2bf  = (short*)(base + 33554432);    //  4 MB: l1 reduce -> l2 fused
  short* temp2 = (short*)(base + 37748736);    //  4 MB: l2 fused -> l2 reduce
  // persistent metadata region (from 64 MB up):
  size_t off = 67108864;
  short* Wbf = (short*)(base + off); off += 655360 * 2;       // 1.25 MB
  int* lists0 = (int*)(base + off); off += 4u * 65536 * 4;    // 1 MB
  int* lists1 = (int*)(base + off); off += 4u * 32768 * 4;    // 512 KB
  int* lists2 = (int*)(base + off); off += 4u * 8192 * 4;     // 128 KB
  int* listF0 = (int*)(base + off); off += 32768 * 4;
  int* listF1 = (int*)(base + off); off += 8192 * 4;
  int* listF2 = (int*)(base + off); off += 2048 * 4;
  int* seg0 = (int*)(base + off); off += 32768 * 4;
  int* seg1 = (int*)(base + off); off += 8192 * 4;
  int* seg2 = (int*)(base + off); off += 2048 * 4;
  int* counts = (int*)(base + off); off += 256;               // [3][8]
  short* zrow = (short*)(base + off); off += 512;             // 256 bf16 zeros

  short* Wp_bf  = Wbf + 0;
  short* Wpf_bf = Wbf + 65536;
  short* Wcz_bf = Wbf + 131072;   // [4][256][256] combined
  short* Wcs_bf = Wbf + 393216;   // [4][256][256] combined

  // wprep zeroes counts+zrow (contiguous) in its last block; runs before bucket_all.
  hipLaunchKernelGGL(wprep_kernel, dim3(2177), dim3(256), 0, stream, W_z, W_z_int,
                     W_s, W_s_int, W_p, W_pf, Wbf, counts);
  hipLaunchKernelGGL(bucket_all_kernel, dim3(416), dim3(256), 0, stream,
                     tmask[0], tmask[1], tmask[2], lists0, lists1, lists2, counts,
                     seg0, seg1, seg2, listF0, listF1, listF2);
  hipLaunchKernelGGL(gather_cvt_kernel, dim3(2048), dim3(256), 0, stream,
                     (const float4*)x, initial_map, (short4v*)d0bf, 65536);

  const int Ms[3] = {65536, 32768, 8192};
  const int Gs[3] = {32768, 8192, 2048};
  const short* dinbf[3] = {d0bf, d1bf, d2bf};
  short* tempL[3] = {temp0, temp1, temp2};
  short* nextbf[3] = {d1bf, d2bf, nullptr};
  int* listsL[3] = {lists0, lists1, lists2};
  int* listFL[3] = {listF0, listF1, listF2};
  int* segL[3] = {seg0, seg1, seg2};

  for (int l = 0; l < 3; ++l) {
    int m = Ms[l], g = Gs[l], r = m / g;
    int grid = m / 32 + 128;  // worst-case dynamic-region capacity
    hipLaunchKernelGGL(fused_gemm, dim3(grid), dim3(256), 0, stream, dinbf[l], om[l],
                       m, listsL[l], counts + l * 8, Wp_bf, Wcz_bf, Wcs_bf, zrow,
                       tempL[l]);

    hipLaunchKernelGGL(reduce_kernel, dim3(g * 32 / 256), dim3(256), 0, stream,
                       tempL[l], r, g, segL[l], (l == 2) ? (float*)d_out : nullptr,
                       nextbf[l]);

    if (l < 2)
      hipLaunchKernelGGL((pf_gemm<0>), dim3(g / 32), dim3(256), 0, stream, nextbf[l],
                         (float*)nullptr, listFL[l], counts + l * 8 + 4, Wpf_bf);
    else
      hipLaunchKernelGGL((pf_gemm<1>), dim3(g / 32), dim3(256), 0, stream,
                         (short*)nullptr, (float*)d_out, listFL[l], counts + l * 8 + 4,
                         Wpf_bf);
  }
}